// Round 11
// baseline (307.693 us; speedup 1.0000x reference)
//
#include <hip/hip_runtime.h>
#include <math.h>

#define NB 256
#define NV 32000
#define ND 1024
#define NT 64

// ---- GEMM config ----
#define GN 64
#define NKB 64             // 1024/16 k-blocks
#define AKBF 8192          // f16 per k-block, fragment order: 8 strips x 2(h,q) x 64 lanes x 8
#define NGBLK (NV / GN)    // 500
#define INV2048F 4.8828125e-4f

// ---- sampling config ----
#define NBIN 1024
#define HSTR 1032
#define HTOT (4 * HSTR)     // 4128 u32 = 16512 B (static LDS)
#define FIX2 4294967296.0
#define SMASK ((1ull << 48) - 1ull)

typedef _Float16 f16x8 __attribute__((ext_vector_type(8)));
typedef _Float16 f16x4 __attribute__((ext_vector_type(4)));
typedef float f32x16 __attribute__((ext_vector_type(16)));

struct RowP2 {
  unsigned long long basePack;
  unsigned long long toppZfix;
  unsigned pfx;
  int ktop;
  float invZ;
  unsigned ustar;
  int m;
  int cEq;
};

__device__ __forceinline__ unsigned mono_enc(float f) {
  unsigned u = __float_as_uint(f);
  return (u & 0x80000000u) ? ~u : (u | 0x80000000u);
}
__device__ __forceinline__ float mono_dec(unsigned u) {
  return (u & 0x80000000u) ? __uint_as_float(u & 0x7FFFFFFFu) : __uint_as_float(~u);
}

// ---------------- convert A: fragment-ordered h/q planes + rowmax zero --------------
__global__ __launch_bounds__(256) void convert_A(const float* __restrict__ hidden,
                                                 _Float16* __restrict__ A3,
                                                 unsigned* __restrict__ rowmax) {
  if (blockIdx.x == 0) rowmax[threadIdx.x] = 0u;  // replaces the memset dispatch
  const int g = blockIdx.x * 256 + threadIdx.x;   // 65536 total
  const int kb = g >> 10, rem = g & 1023, r = rem >> 2, c = rem & 3;
  const float4 a4 = *(const float4*)(hidden + (size_t)r * ND + kb * 16 + c * 4);
  const float v[4] = {a4.x, a4.y, a4.z, a4.w};
  f16x4 h4, q4;
#pragma unroll
  for (int q = 0; q < 4; q++) {
    const _Float16 hh = (_Float16)v[q];
    h4[q] = hh;
    q4[q] = (_Float16)((v[q] - (float)hh) * 2048.0f);
  }
  const int s = r >> 5, l31 = r & 31;
  const int lh = c >> 1, j4 = (c & 1) * 4;
  const int lane = l31 + (lh << 5);
  _Float16* base = A3 + (size_t)kb * AKBF;
  *(f16x4*)(base + ((s * 2 + 0) * 64 + lane) * 8 + j4) = h4;
  *(f16x4*)(base + ((s * 2 + 1) * 64 + lane) * 8 + j4) = q4;
}

// ---------------- MFMA f16-split GEMM: fully register-resident, ZERO barriers -------
// R10 lesson: the B LDS path (BCONV->ds_write->lgkm->barrier->ds_read) was the last
// serial chain. B's MFMA fragment is lane-contiguous in emb (lane l reads
// emb[n0+l31][kb*16+ka..+7] = 32B), so load it per-lane and split h/q in registers.
// In-register BCONV (~64 VALU/iter) co-issues with MFMA (separate pipes). No LDS, no
// barriers in the main loop; each wave free-runs a 2-deep load->MFMA pipeline.
__global__ __launch_bounds__(256, 2) void gemm_f16s(
    const float* __restrict__ Bm, const _Float16* __restrict__ A3,
    const float* __restrict__ temp, unsigned* __restrict__ rowmax,
    float* __restrict__ C) {
  __shared__ float s_invT[256];
  __shared__ unsigned s_pm[256];

  const int t = threadIdx.x;
  const int l = t & 63, w = t >> 6;
  const int n0 = blockIdx.x * GN;
  s_invT[t] = 1.0f / temp[t];
  s_pm[t] = 0u;
  __syncthreads();  // required: no main-loop barriers keep waves in lockstep anymore

  f32x16 accH[2][2] = {};  // [strip][ncol] h*h'
  f32x16 accC[2][2] = {};  // h*q' + q*h' (scaled by 2048)

  const int l31 = l & 31, lh = l >> 5;
  const int ka = lh * 8;
  const int mb = w * 64;

  // per-lane B row pointers (fragment-native): row n0+l31 and n0+32+l31, k = ka..
  const float* b0p = Bm + (size_t)(n0 + l31) * ND + ka;
  const float* b1p = Bm + (size_t)(n0 + 32 + l31) * ND + ka;
  const _Float16* aB = A3 + 2048 * w + l * 8;

  f16x8 eh0, eh1, eq0, eq1;            // A fragments (even/odd)
  f16x8 oh0, oh1, oq0, oq1;
  float4 ebf0a, ebf0b, ebf1a, ebf1b;   // B f32 (even/odd): 8 per col x 2 cols
  float4 obf0a, obf0b, obf1a, obf1b;

#define LOADA(P, KB)                                                  \
  do {                                                                \
    const _Float16* ap_ = aB + (size_t)(KB) * AKBF;                   \
    P##h0 = *(const f16x8*)(ap_);                                     \
    P##q0 = *(const f16x8*)(ap_ + 512);                               \
    P##h1 = *(const f16x8*)(ap_ + 1024);                              \
    P##q1 = *(const f16x8*)(ap_ + 1536);                              \
  } while (0)

#define LOADB(P, KB)                                                  \
  do {                                                                \
    const float* p0_ = b0p + (size_t)(KB) * 16;                       \
    const float* p1_ = b1p + (size_t)(KB) * 16;                       \
    P##bf0a = *(const float4*)(p0_);                                  \
    P##bf0b = *(const float4*)(p0_ + 4);                              \
    P##bf1a = *(const float4*)(p1_);                                  \
    P##bf1b = *(const float4*)(p1_ + 4);                              \
  } while (0)

#define COMPUTE(P)                                                                          \
  do {                                                                                      \
    const float s0_[8] = {P##bf0a.x, P##bf0a.y, P##bf0a.z, P##bf0a.w,                       \
                          P##bf0b.x, P##bf0b.y, P##bf0b.z, P##bf0b.w};                      \
    const float s1_[8] = {P##bf1a.x, P##bf1a.y, P##bf1a.z, P##bf1a.w,                       \
                          P##bf1b.x, P##bf1b.y, P##bf1b.z, P##bf1b.w};                      \
    f16x8 b0h_, b0q_, b1h_, b1q_;                                                           \
    _Pragma("unroll") for (int j_ = 0; j_ < 8; j_++) {                                      \
      const _Float16 h0_ = (_Float16)s0_[j_];                                               \
      b0h_[j_] = h0_;                                                                       \
      b0q_[j_] = (_Float16)((s0_[j_] - (float)h0_) * 2048.0f);                              \
      const _Float16 h1_ = (_Float16)s1_[j_];                                               \
      b1h_[j_] = h1_;                                                                       \
      b1q_[j_] = (_Float16)((s1_[j_] - (float)h1_) * 2048.0f);                              \
    }                                                                                       \
    accH[0][0] = __builtin_amdgcn_mfma_f32_32x32x16_f16(P##h0, b0h_, accH[0][0], 0, 0, 0);  \
    accH[0][1] = __builtin_amdgcn_mfma_f32_32x32x16_f16(P##h0, b1h_, accH[0][1], 0, 0, 0);  \
    accH[1][0] = __builtin_amdgcn_mfma_f32_32x32x16_f16(P##h1, b0h_, accH[1][0], 0, 0, 0);  \
    accH[1][1] = __builtin_amdgcn_mfma_f32_32x32x16_f16(P##h1, b1h_, accH[1][1], 0, 0, 0);  \
    accC[0][0] = __builtin_amdgcn_mfma_f32_32x32x16_f16(P##h0, b0q_, accC[0][0], 0, 0, 0);  \
    accC[0][1] = __builtin_amdgcn_mfma_f32_32x32x16_f16(P##h0, b1q_, accC[0][1], 0, 0, 0);  \
    accC[1][0] = __builtin_amdgcn_mfma_f32_32x32x16_f16(P##h1, b0q_, accC[1][0], 0, 0, 0);  \
    accC[1][1] = __builtin_amdgcn_mfma_f32_32x32x16_f16(P##h1, b1q_, accC[1][1], 0, 0, 0);  \
    accC[0][0] = __builtin_amdgcn_mfma_f32_32x32x16_f16(P##q0, b0h_, accC[0][0], 0, 0, 0);  \
    accC[0][1] = __builtin_amdgcn_mfma_f32_32x32x16_f16(P##q0, b1h_, accC[0][1], 0, 0, 0);  \
    accC[1][0] = __builtin_amdgcn_mfma_f32_32x32x16_f16(P##q1, b0h_, accC[1][0], 0, 0, 0);  \
    accC[1][1] = __builtin_amdgcn_mfma_f32_32x32x16_f16(P##q1, b1h_, accC[1][1], 0, 0, 0);  \
  } while (0)

  // ---- prologue: 2-deep prefetch ----
  LOADA(e, 0); LOADB(e, 0);
  __builtin_amdgcn_sched_barrier(0);
  LOADA(o, 1); LOADB(o, 1);
  __builtin_amdgcn_sched_barrier(0);

  // invariant entering pair kb: e = tile(kb), o = tile(kb+1)
  for (int kb = 0; kb < 62; kb += 2) {
    COMPUTE(e);
    __builtin_amdgcn_sched_barrier(0);
    LOADA(e, kb + 2); LOADB(e, kb + 2);
    __builtin_amdgcn_sched_barrier(0);
    COMPUTE(o);
    __builtin_amdgcn_sched_barrier(0);
    LOADA(o, kb + 3); LOADB(o, kb + 3);
    __builtin_amdgcn_sched_barrier(0);
  }
  COMPUTE(e);   // tile 62
  __builtin_amdgcn_sched_barrier(0);
  COMPUTE(o);   // tile 63

#undef LOADA
#undef LOADB
#undef COMPUTE

#pragma unroll
  for (int mi = 0; mi < 2; mi++) {
#pragma unroll
    for (int r = 0; r < 16; r++) {
      const int row = mb + mi * 32 + (r & 3) + 8 * (r >> 2) + 4 * lh;
      const float it = s_invT[row];
      float v0 = (accH[mi][0][r] + accC[mi][0][r] * INV2048F) * it;
      float v1 = (accH[mi][1][r] + accC[mi][1][r] * INV2048F) * it;
      C[(size_t)row * NV + n0 + l31] = v0;
      C[(size_t)row * NV + n0 + 32 + l31] = v1;
      float mx = fmaxf(v0, v1);
#pragma unroll
      for (int o = 1; o < 32; o <<= 1) mx = fmaxf(mx, __shfl_xor(mx, o));
      if (l31 == 0) atomicMax(&s_pm[row], mono_enc(mx));
    }
  }
  __syncthreads();
  atomicMax(&rowmax[t], s_pm[t]);
}

// ---------------- fused per-row sampler: global row in place, LDS = hist only -------
// (unchanged from R10)
__global__ __launch_bounds__(1024) void sample_row(
    float* __restrict__ buf, const unsigned* __restrict__ rowmax,
    const int* __restrict__ toks, const float* __restrict__ pres,
    const float* __restrict__ freq, const float* __restrict__ temp,
    const float* __restrict__ topp_a, const int* __restrict__ topk_a) {
  __shared__ unsigned hist[HTOT];                       // 16512 B
  unsigned long long* suf = (unsigned long long*)hist;  // aliases first 8192 B
  __shared__ unsigned long long wtot16[16];
  __shared__ int s_tok[NT];
  __shared__ int s_bs;
  __shared__ RowP2 sp;

  const int b = blockIdx.x, t = threadIdx.x;
  const int cp = (t >> 6) & 1;
  unsigned* loP = hist + cp * HSTR;
  unsigned* hcP = hist + 2 * HSTR + cp * HSTR;
  float* row = buf + (size_t)b * NV;

#define HACC(K, BIN)                                                            \
  do {                                                                          \
    unsigned long long m_ = (unsigned long long)(((K) & 0x7FFFFFu) | 0x800000u);\
    const int sh_ = (int)((K) >> 23) - 118;                                     \
    const unsigned long long f_ =                                               \
        (sh_ >= 0) ? (m_ << sh_) : ((sh_ > -24) ? (m_ >> (-sh_)) : 0ull);       \
    const unsigned flo_ = (unsigned)f_;                                         \
    const unsigned old_ = atomicAdd(&loP[BIN], flo_);                           \
    const unsigned hc_ = 0x10000u + (unsigned)(f_ >> 32) +                      \
                         ((old_ + flo_ < flo_) ? 1u : 0u);                      \
    atomicAdd(&hcP[BIN], hc_);                                                  \
  } while (0)

  if (t < NT) s_tok[t] = toks[b * NT + t];
  for (int i = t; i < HTOT; i += 1024) hist[i] = 0u;
  __syncthreads();

  if (t < NT) {
    const int tk = s_tok[t];
    bool first = true; int cnt = 0;
    for (int j = 0; j < NT; j++)
      if (s_tok[j] == tk) { if (j < t) first = false; cnt++; }
    if (first) row[tk] -= (freq[b] * (float)cnt + pres[b]) / temp[b];
  }
  __syncthreads();

  const float M = mono_dec(rowmax[b]);
  for (int i4 = t; i4 < NV / 4; i4 += 1024) {
    float4 x4 = *(const float4*)(row + i4 * 4);
    float4 e4;
    e4.x = expf(x4.x - M); e4.y = expf(x4.y - M);
    e4.z = expf(x4.z - M); e4.w = expf(x4.w - M);
    *(float4*)(row + i4 * 4) = e4;
    unsigned k;
    k = __float_as_uint(e4.x); if (k) HACC(k, k >> 20);
    k = __float_as_uint(e4.y); if (k) HACC(k, k >> 20);
    k = __float_as_uint(e4.z); if (k) HACC(k, k >> 20);
    k = __float_as_uint(e4.w); if (k) HACC(k, k >> 20);
  }
  __syncthreads();

  const int lane = t & 63, wv = t >> 6;
  for (int level = 0; level < 3; level++) {
    const unsigned lo0 = hist[t], lo1 = hist[HSTR + t];
    const unsigned hc0 = hist[2 * HSTR + t], hc1 = hist[3 * HSTR + t];
    const unsigned c = (hc0 >> 16) + (hc1 >> 16);
    const unsigned long long sum =
        (((unsigned long long)((hc0 & 0xFFFFu) + (hc1 & 0xFFFFu))) << 32) +
        (unsigned long long)lo0 + (unsigned long long)lo1;
    unsigned long long sv = ((unsigned long long)c << 48) + sum;
#pragma unroll
    for (int off = 1; off < 64; off <<= 1) {
      const unsigned long long up = __shfl_down(sv, off, 64);
      if (lane + off < 64) sv += up;
    }
    if (lane == 0) wtot16[wv] = sv;
    if (t == 0) s_bs = NBIN - 1;
    __syncthreads();
    unsigned long long add = 0ull, tot = 0ull;
#pragma unroll
    for (int w2 = 0; w2 < 16; w2++) {
      const unsigned long long x = wtot16[w2];
      tot += x;
      add += (w2 > wv) ? x : 0ull;
    }
    const unsigned long long mySuf = sv + add;
    suf[t] = mySuf;
    const unsigned long long totalP = tot;
    __syncthreads();

    unsigned long long base, toppZ;
    int ktop_;
    if (level == 0) {
      ktop_ = topk_a[b];
      unsigned long long Zfix = totalP & SMASK;
      if (!Zfix) Zfix = 1ull;
      toppZ = (unsigned long long)((double)topp_a[b] * (double)Zfix);
      base = 0ull;
    } else {
      base = sp.basePack; toppZ = sp.toppZfix; ktop_ = sp.ktop;
    }

    {
      const unsigned long long sG = base + mySuf;
      const bool A = ((long long)(sG >> 48) < (long long)ktop_) && ((sG & SMASK) <= toppZ);
      const unsigned long long sP = base + ((t > 0) ? suf[t - 1] : totalP);
      const bool Ap = ((long long)(sP >> 48) < (long long)ktop_) && ((sP & SMASK) <= toppZ);
      if (A && !Ap) s_bs = t;
    }
    __syncthreads();
    if (t == 0) {
      const int bs = s_bs;
      const unsigned long long newBase = base + suf[bs];
      if (level == 0) {
        unsigned long long Zfix = totalP & SMASK;
        if (!Zfix) Zfix = 1ull;
        sp.invZ = (float)(FIX2 / (double)Zfix);
      }
      if (level < 2) {
        sp.basePack = newBase;
        sp.toppZfix = toppZ;
        sp.ktop = ktop_;
        sp.pfx = (level == 0) ? (unsigned)bs : ((sp.pfx << 10) | (unsigned)bs);
      } else {
        const unsigned ustar = (sp.pfx << 10) | (unsigned)bs;
        const unsigned long long raw = ((bs > 0) ? suf[bs - 1] : totalP) - suf[bs];
        const int cEq = (int)(raw >> 48);
        const long long Chi = (long long)(newBase >> 48);
        const unsigned long long Shi = newBase & SMASK;
        long long m = cEq;
        const long long lim = (long long)ktop_ - Chi;
        if (lim < m) m = lim;
        const double tf = (double)__uint_as_float(ustar) * FIX2;
        const double rem = (double)(toppZ - Shi);
        const double Rd = floor(rem / tf) + 1.0;
        if (Rd < (double)m) m = (long long)Rd;
        if (m < 1) m = 1;
        sp.ustar = ustar; sp.m = (int)m; sp.cEq = cEq;
      }
    }
    __syncthreads();

    if (level < 2) {
      for (int i = t; i < HTOT; i += 1024) hist[i] = 0u;
      __syncthreads();
      const unsigned pfx = sp.pfx;
      const int ms = (level == 0) ? 20 : 10;
      const int bsh = (level == 0) ? 10 : 0;
      for (int i4 = t; i4 < NV / 4; i4 += 1024) {
        float4 e4 = *(const float4*)(row + i4 * 4);
        unsigned k;
        k = __float_as_uint(e4.x); if (k && (k >> ms) == pfx) HACC(k, (k >> bsh) & 1023u);
        k = __float_as_uint(e4.y); if (k && (k >> ms) == pfx) HACC(k, (k >> bsh) & 1023u);
        k = __float_as_uint(e4.z); if (k && (k >> ms) == pfx) HACC(k, (k >> bsh) & 1023u);
        k = __float_as_uint(e4.w); if (k && (k >> ms) == pfx) HACC(k, (k >> bsh) & 1023u);
      }
      __syncthreads();
    }
  }
#undef HACC

  const unsigned ustar = sp.ustar;
  const float invZ = sp.invZ;
  if (sp.m >= sp.cEq) {
    for (int i4 = t; i4 < NV / 4; i4 += 1024) {
      float4 e4 = *(const float4*)(row + i4 * 4);
      float4 o4;
      unsigned k;
      k = __float_as_uint(e4.x); o4.x = (k >= ustar) ? e4.x * invZ : 0.f;
      k = __float_as_uint(e4.y); o4.y = (k >= ustar) ? e4.y * invZ : 0.f;
      k = __float_as_uint(e4.z); o4.z = (k >= ustar) ? e4.z * invZ : 0.f;
      k = __float_as_uint(e4.w); o4.w = (k >= ustar) ? e4.w * invZ : 0.f;
      *(float4*)(row + i4 * 4) = o4;
    }
  } else {
    const int m = sp.m;
    unsigned* rk = hist;
    const int base0 = t * 32;
    const int end0 = (base0 + 32 < NV) ? base0 + 32 : NV;
    int myc = 0;
    for (int v = base0; v < end0; v++)
      myc += (__float_as_uint(row[v]) == ustar);
    rk[t] = (unsigned)myc;
    __syncthreads();
    for (int off = 1; off < 1024; off <<= 1) {
      const unsigned a0 = rk[t];
      const unsigned an = (t >= off) ? rk[t - off] : 0u;
      __syncthreads();
      rk[t] = a0 + an;
      __syncthreads();
    }
    int r = (t > 0) ? (int)rk[t - 1] : 0;
    for (int v = base0; v < end0; v++) {
      const unsigned k = __float_as_uint(row[v]);
      float o = (k > ustar) ? row[v] * invZ : 0.f;
      if (k == ustar) { o = (r < m) ? row[v] * invZ : 0.f; r++; }
      row[v] = o;
    }
  }
}

extern "C" void kernel_launch(void* const* d_in, const int* in_sizes, int n_in,
                              void* d_out, int out_size, void* d_ws, size_t ws_size,
                              hipStream_t stream) {
  (void)in_sizes; (void)n_in; (void)out_size; (void)ws_size;
  const float* hidden = (const float*)d_in[0];
  const float* emb    = (const float*)d_in[1];
  const int*   toks   = (const int*)d_in[2];
  const float* pres   = (const float*)d_in[3];
  const float* freq   = (const float*)d_in[4];
  const float* temp   = (const float*)d_in[5];
  const float* topp   = (const float*)d_in[6];
  const int*   topk   = (const int*)d_in[7];
  float* out = (float*)d_out;

  // ws layout: A3 (64*16384 = 1,048,576 B) + rowmax (1,024 B, zeroed by convert_A)
  const size_t offA3 = 0;
  const size_t offRM = 1048576;

  _Float16* A3 = (_Float16*)((char*)d_ws + offA3);
  unsigned* rowmax = (unsigned*)((char*)d_ws + offRM);

  convert_A<<<256, 256, 0, stream>>>(hidden, A3, rowmax);
  gemm_f16s<<<NGBLK, 256, 0, stream>>>(emb, A3, temp, rowmax, out);
  sample_row<<<NB, 1024, 0, stream>>>(out, rowmax, toks, pres, freq,
                                      temp, topp, topk);
}

// Round 12
// 277.160 us; speedup vs baseline: 1.1102x; 1.1102x over previous
//
#include <hip/hip_runtime.h>
#include <math.h>

#define NB 256
#define NV 32000
#define ND 1024
#define NT 64

// ---- GEMM config ----
#define GN 64
#define BSTR 40            // B row stride (f16): [h x16][q x16][pad x8]
#define NKB 64             // 1024/16 k-blocks
#define AKBF 8192          // f16 per k-block, fragment order
#define NGBLK (NV / GN)    // 500
#define INV2048F 4.8828125e-4f

// ---- sampling config ----
#define NBIN 1024
#define HSTR 1032
#define HTOT (4 * HSTR)     // 4128 u32 = 16512 B (static LDS)
#define FIX2 4294967296.0
#define SMASK ((1ull << 48) - 1ull)

typedef _Float16 f16x8 __attribute__((ext_vector_type(8)));
typedef _Float16 f16x4 __attribute__((ext_vector_type(4)));
typedef float f32x16 __attribute__((ext_vector_type(16)));

struct RowP2 {
  unsigned long long basePack;
  unsigned long long toppZfix;
  unsigned pfx;
  int ktop;
  float invZ;
  unsigned ustar;
  int m;
  int cEq;
};

__device__ __forceinline__ unsigned mono_enc(float f) {
  unsigned u = __float_as_uint(f);
  return (u & 0x80000000u) ? ~u : (u | 0x80000000u);
}
__device__ __forceinline__ float mono_dec(unsigned u) {
  return (u & 0x80000000u) ? __uint_as_float(u & 0x7FFFFFFFu) : __uint_as_float(~u);
}

// ---------------- convert A: fragment-ordered h/q planes + rowmax zero --------------
__global__ __launch_bounds__(256) void convert_A(const float* __restrict__ hidden,
                                                 _Float16* __restrict__ A3,
                                                 unsigned* __restrict__ rowmax) {
  if (blockIdx.x == 0) rowmax[threadIdx.x] = 0u;
  const int g = blockIdx.x * 256 + threadIdx.x;   // 65536 total
  const int kb = g >> 10, rem = g & 1023, r = rem >> 2, c = rem & 3;
  const float4 a4 = *(const float4*)(hidden + (size_t)r * ND + kb * 16 + c * 4);
  const float v[4] = {a4.x, a4.y, a4.z, a4.w};
  f16x4 h4, q4;
#pragma unroll
  for (int q = 0; q < 4; q++) {
    const _Float16 hh = (_Float16)v[q];
    h4[q] = hh;
    q4[q] = (_Float16)((v[q] - (float)hh) * 2048.0f);
  }
  const int s = r >> 5, l31 = r & 31;
  const int lh = c >> 1, j4 = (c & 1) * 4;
  const int lane = l31 + (lh << 5);
  _Float16* base = A3 + (size_t)kb * AKBF;
  *(f16x4*)(base + ((s * 2 + 0) * 64 + lane) * 8 + j4) = h4;
  *(f16x4*)(base + ((s * 2 + 1) * 64 + lane) * 8 + j4) = q4;
}

// ---------------- MFMA f16-split GEMM: A in registers, B in LDS dbuf (exact R10) ----
// R11 lesson: per-wave in-register B convert = ~128cy dependent VALU vs 96cy MFMA,
// redundant x4 across waves -> LDS path (convert once, share via LDS) is faster.
__global__ __launch_bounds__(256, 2) void gemm_f16s(
    const float* __restrict__ Bm, const _Float16* __restrict__ A3,
    const float* __restrict__ temp, unsigned* __restrict__ rowmax,
    float* __restrict__ C) {
  __shared__ _Float16 Bls[2][GN * BSTR];  // 10,240 B
  __shared__ float s_invT[256];
  __shared__ unsigned s_pm[256];

  const int t = threadIdx.x;
  const int l = t & 63, w = t >> 6;
  const int n0 = blockIdx.x * GN;
  s_invT[t] = 1.0f / temp[t];
  s_pm[t] = 0u;

  f32x16 accH[2][2] = {};
  f32x16 accC[2][2] = {};

  const int bn = t >> 2, bk4 = (t & 3) * 4;
  const int l31 = l & 31, lh = l >> 5;
  const int ka = lh * 8;
  const int mb = w * 64;

  const float* browp = Bm + (size_t)(n0 + bn) * ND + bk4;
  const _Float16* aB = A3 + 2048 * w + l * 8;

  f16x8 eh0, eh1, eq0, eq1;
  f16x8 oh0, oh1, oq0, oq1;

#define LOADA(P, KB)                                                  \
  do {                                                                \
    const _Float16* ap_ = aB + (size_t)(KB) * AKBF;                   \
    P##h0 = *(const f16x8*)(ap_);                                     \
    P##q0 = *(const f16x8*)(ap_ + 512);                               \
    P##h1 = *(const f16x8*)(ap_ + 1024);                              \
    P##q1 = *(const f16x8*)(ap_ + 1536);                              \
  } while (0)

#define BCONV(BV, DST)                                                \
  do {                                                                \
    f16x4 h4_, q4_;                                                   \
    const float vv_[4] = {(BV).x, (BV).y, (BV).z, (BV).w};            \
    _Pragma("unroll") for (int j_ = 0; j_ < 4; j_++) {                \
      const _Float16 h_ = (_Float16)vv_[j_];                          \
      h4_[j_] = h_;                                                   \
      q4_[j_] = (_Float16)((vv_[j_] - (float)h_) * 2048.0f);          \
    }                                                                 \
    _Float16* prow_ = (DST) + bn * BSTR;                              \
    *(f16x4*)(prow_ + bk4) = h4_;                                     \
    *(f16x4*)(prow_ + 16 + bk4) = q4_;                                \
  } while (0)

#define COMPUTE(P, CUR)                                                                     \
  do {                                                                                      \
    const _Float16* Bp_ = &Bls[CUR][0] + (size_t)l31 * BSTR + ka;                           \
    f16x8 b0h_ = *(const f16x8*)(Bp_);                                                      \
    f16x8 b1h_ = *(const f16x8*)(Bp_ + 32 * BSTR);                                          \
    accH[0][0] = __builtin_amdgcn_mfma_f32_32x32x16_f16(P##h0, b0h_, accH[0][0], 0, 0, 0);  \
    accH[0][1] = __builtin_amdgcn_mfma_f32_32x32x16_f16(P##h0, b1h_, accH[0][1], 0, 0, 0);  \
    accH[1][0] = __builtin_amdgcn_mfma_f32_32x32x16_f16(P##h1, b0h_, accH[1][0], 0, 0, 0);  \
    accH[1][1] = __builtin_amdgcn_mfma_f32_32x32x16_f16(P##h1, b1h_, accH[1][1], 0, 0, 0);  \
    f16x8 b0q_ = *(const f16x8*)(Bp_ + 16);                                                 \
    f16x8 b1q_ = *(const f16x8*)(Bp_ + 32 * BSTR + 16);                                     \
    accC[0][0] = __builtin_amdgcn_mfma_f32_32x32x16_f16(P##h0, b0q_, accC[0][0], 0, 0, 0);  \
    accC[0][1] = __builtin_amdgcn_mfma_f32_32x32x16_f16(P##h0, b1q_, accC[0][1], 0, 0, 0);  \
    accC[1][0] = __builtin_amdgcn_mfma_f32_32x32x16_f16(P##h1, b0q_, accC[1][0], 0, 0, 0);  \
    accC[1][1] = __builtin_amdgcn_mfma_f32_32x32x16_f16(P##h1, b1q_, accC[1][1], 0, 0, 0);  \
    accC[0][0] = __builtin_amdgcn_mfma_f32_32x32x16_f16(P##q0, b0h_, accC[0][0], 0, 0, 0);  \
    accC[0][1] = __builtin_amdgcn_mfma_f32_32x32x16_f16(P##q0, b1h_, accC[0][1], 0, 0, 0);  \
    accC[1][0] = __builtin_amdgcn_mfma_f32_32x32x16_f16(P##q1, b0h_, accC[1][0], 0, 0, 0);  \
    accC[1][1] = __builtin_amdgcn_mfma_f32_32x32x16_f16(P##q1, b1h_, accC[1][1], 0, 0, 0);  \
  } while (0)

  LOADA(e, 0);
  __builtin_amdgcn_sched_barrier(0);
  float4 bv0 = *(const float4*)(browp);
  __builtin_amdgcn_sched_barrier(0);
  LOADA(o, 1);
  __builtin_amdgcn_sched_barrier(0);
  float4 bvA = *(const float4*)(browp + 16);
  __builtin_amdgcn_sched_barrier(0);
  BCONV(bv0, &Bls[0][0]);
  asm volatile("s_waitcnt lgkmcnt(0)\ns_barrier" ::: "memory");

  float4 bvB;
  for (int kb = 0; kb < 62; kb += 2) {
    COMPUTE(e, 0);
    __builtin_amdgcn_sched_barrier(0);
    LOADA(e, kb + 2);
    __builtin_amdgcn_sched_barrier(0);
    bvB = *(const float4*)(browp + (size_t)(kb + 2) * 16);
    __builtin_amdgcn_sched_barrier(0);
    BCONV(bvA, &Bls[1][0]);
    asm volatile("s_waitcnt lgkmcnt(0)\ns_barrier" ::: "memory");

    COMPUTE(o, 1);
    __builtin_amdgcn_sched_barrier(0);
    LOADA(o, kb + 3);
    __builtin_amdgcn_sched_barrier(0);
    bvA = *(const float4*)(browp + (size_t)(kb + 3) * 16);
    __builtin_amdgcn_sched_barrier(0);
    BCONV(bvB, &Bls[0][0]);
    asm volatile("s_waitcnt lgkmcnt(0)\ns_barrier" ::: "memory");
  }
  COMPUTE(e, 0);
  __builtin_amdgcn_sched_barrier(0);
  BCONV(bvA, &Bls[1][0]);
  asm volatile("s_waitcnt lgkmcnt(0)\ns_barrier" ::: "memory");
  COMPUTE(o, 1);

#undef LOADA
#undef BCONV
#undef COMPUTE

#pragma unroll
  for (int mi = 0; mi < 2; mi++) {
#pragma unroll
    for (int r = 0; r < 16; r++) {
      const int row = mb + mi * 32 + (r & 3) + 8 * (r >> 2) + 4 * lh;
      const float it = s_invT[row];
      float v0 = (accH[mi][0][r] + accC[mi][0][r] * INV2048F) * it;
      float v1 = (accH[mi][1][r] + accC[mi][1][r] * INV2048F) * it;
      C[(size_t)row * NV + n0 + l31] = v0;
      C[(size_t)row * NV + n0 + 32 + l31] = v1;
      float mx = fmaxf(v0, v1);
#pragma unroll
      for (int o = 1; o < 32; o <<= 1) mx = fmaxf(mx, __shfl_xor(mx, o));
      if (l31 == 0) atomicMax(&s_pm[row], mono_enc(mx));
    }
  }
  __syncthreads();
  atomicMax(&rowmax[t], s_pm[t]);
}

// ---------------- sample_select: penalties + exp + 3-level radix -> params ----------
// (R10's sample_row minus the filter pass; writes RowP2 to global for the filter.)
__global__ __launch_bounds__(1024) void sample_select(
    float* __restrict__ buf, const unsigned* __restrict__ rowmax,
    const int* __restrict__ toks, const float* __restrict__ pres,
    const float* __restrict__ freq, const float* __restrict__ temp,
    const float* __restrict__ topp_a, const int* __restrict__ topk_a,
    RowP2* __restrict__ params) {
  __shared__ unsigned hist[HTOT];
  unsigned long long* suf = (unsigned long long*)hist;
  __shared__ unsigned long long wtot16[16];
  __shared__ int s_tok[NT];
  __shared__ int s_bs;
  __shared__ RowP2 sp;

  const int b = blockIdx.x, t = threadIdx.x;
  const int cp = (t >> 6) & 1;
  unsigned* loP = hist + cp * HSTR;
  unsigned* hcP = hist + 2 * HSTR + cp * HSTR;
  float* row = buf + (size_t)b * NV;

#define HACC(K, BIN)                                                            \
  do {                                                                          \
    unsigned long long m_ = (unsigned long long)(((K) & 0x7FFFFFu) | 0x800000u);\
    const int sh_ = (int)((K) >> 23) - 118;                                     \
    const unsigned long long f_ =                                               \
        (sh_ >= 0) ? (m_ << sh_) : ((sh_ > -24) ? (m_ >> (-sh_)) : 0ull);       \
    const unsigned flo_ = (unsigned)f_;                                         \
    const unsigned old_ = atomicAdd(&loP[BIN], flo_);                           \
    const unsigned hc_ = 0x10000u + (unsigned)(f_ >> 32) +                      \
                         ((old_ + flo_ < flo_) ? 1u : 0u);                      \
    atomicAdd(&hcP[BIN], hc_);                                                  \
  } while (0)

  if (t < NT) s_tok[t] = toks[b * NT + t];
  for (int i = t; i < HTOT; i += 1024) hist[i] = 0u;
  __syncthreads();

  if (t < NT) {
    const int tk = s_tok[t];
    bool first = true; int cnt = 0;
    for (int j = 0; j < NT; j++)
      if (s_tok[j] == tk) { if (j < t) first = false; cnt++; }
    if (first) row[tk] -= (freq[b] * (float)cnt + pres[b]) / temp[b];
  }
  __syncthreads();

  const float M = mono_dec(rowmax[b]);
  for (int i4 = t; i4 < NV / 4; i4 += 1024) {
    float4 x4 = *(const float4*)(row + i4 * 4);
    float4 e4;
    e4.x = expf(x4.x - M); e4.y = expf(x4.y - M);
    e4.z = expf(x4.z - M); e4.w = expf(x4.w - M);
    *(float4*)(row + i4 * 4) = e4;
    unsigned k;
    k = __float_as_uint(e4.x); if (k) HACC(k, k >> 20);
    k = __float_as_uint(e4.y); if (k) HACC(k, k >> 20);
    k = __float_as_uint(e4.z); if (k) HACC(k, k >> 20);
    k = __float_as_uint(e4.w); if (k) HACC(k, k >> 20);
  }
  __syncthreads();

  const int lane = t & 63, wv = t >> 6;
  for (int level = 0; level < 3; level++) {
    const unsigned lo0 = hist[t], lo1 = hist[HSTR + t];
    const unsigned hc0 = hist[2 * HSTR + t], hc1 = hist[3 * HSTR + t];
    const unsigned c = (hc0 >> 16) + (hc1 >> 16);
    const unsigned long long sum =
        (((unsigned long long)((hc0 & 0xFFFFu) + (hc1 & 0xFFFFu))) << 32) +
        (unsigned long long)lo0 + (unsigned long long)lo1;
    unsigned long long sv = ((unsigned long long)c << 48) + sum;
#pragma unroll
    for (int off = 1; off < 64; off <<= 1) {
      const unsigned long long up = __shfl_down(sv, off, 64);
      if (lane + off < 64) sv += up;
    }
    if (lane == 0) wtot16[wv] = sv;
    if (t == 0) s_bs = NBIN - 1;
    __syncthreads();
    unsigned long long add = 0ull, tot = 0ull;
#pragma unroll
    for (int w2 = 0; w2 < 16; w2++) {
      const unsigned long long x = wtot16[w2];
      tot += x;
      add += (w2 > wv) ? x : 0ull;
    }
    const unsigned long long mySuf = sv + add;
    suf[t] = mySuf;
    const unsigned long long totalP = tot;
    __syncthreads();

    unsigned long long base, toppZ;
    int ktop_;
    if (level == 0) {
      ktop_ = topk_a[b];
      unsigned long long Zfix = totalP & SMASK;
      if (!Zfix) Zfix = 1ull;
      toppZ = (unsigned long long)((double)topp_a[b] * (double)Zfix);
      base = 0ull;
    } else {
      base = sp.basePack; toppZ = sp.toppZfix; ktop_ = sp.ktop;
    }

    {
      const unsigned long long sG = base + mySuf;
      const bool A = ((long long)(sG >> 48) < (long long)ktop_) && ((sG & SMASK) <= toppZ);
      const unsigned long long sP = base + ((t > 0) ? suf[t - 1] : totalP);
      const bool Ap = ((long long)(sP >> 48) < (long long)ktop_) && ((sP & SMASK) <= toppZ);
      if (A && !Ap) s_bs = t;
    }
    __syncthreads();
    if (t == 0) {
      const int bs = s_bs;
      const unsigned long long newBase = base + suf[bs];
      if (level == 0) {
        unsigned long long Zfix = totalP & SMASK;
        if (!Zfix) Zfix = 1ull;
        sp.invZ = (float)(FIX2 / (double)Zfix);
      }
      if (level < 2) {
        sp.basePack = newBase;
        sp.toppZfix = toppZ;
        sp.ktop = ktop_;
        sp.pfx = (level == 0) ? (unsigned)bs : ((sp.pfx << 10) | (unsigned)bs);
      } else {
        const unsigned ustar = (sp.pfx << 10) | (unsigned)bs;
        const unsigned long long raw = ((bs > 0) ? suf[bs - 1] : totalP) - suf[bs];
        const int cEq = (int)(raw >> 48);
        const long long Chi = (long long)(newBase >> 48);
        const unsigned long long Shi = newBase & SMASK;
        long long m = cEq;
        const long long lim = (long long)ktop_ - Chi;
        if (lim < m) m = lim;
        const double tf = (double)__uint_as_float(ustar) * FIX2;
        const double rem = (double)(toppZ - Shi);
        const double Rd = floor(rem / tf) + 1.0;
        if (Rd < (double)m) m = (long long)Rd;
        if (m < 1) m = 1;
        sp.ustar = ustar; sp.m = (int)m; sp.cEq = cEq;
        params[b] = sp;
      }
    }
    __syncthreads();

    if (level < 2) {
      for (int i = t; i < HTOT; i += 1024) hist[i] = 0u;
      __syncthreads();
      const unsigned pfx = sp.pfx;
      const int ms = (level == 0) ? 20 : 10;
      const int bsh = (level == 0) ? 10 : 0;
      for (int i4 = t; i4 < NV / 4; i4 += 1024) {
        float4 e4 = *(const float4*)(row + i4 * 4);
        unsigned k;
        k = __float_as_uint(e4.x); if (k && (k >> ms) == pfx) HACC(k, (k >> bsh) & 1023u);
        k = __float_as_uint(e4.y); if (k && (k >> ms) == pfx) HACC(k, (k >> bsh) & 1023u);
        k = __float_as_uint(e4.z); if (k && (k >> ms) == pfx) HACC(k, (k >> bsh) & 1023u);
        k = __float_as_uint(e4.w); if (k && (k >> ms) == pfx) HACC(k, (k >> bsh) & 1023u);
      }
      __syncthreads();
    }
  }
#undef HACC
}

// ---------------- s3_filter: streaming filter, 8 blocks/row (R2-proven) -------------
__global__ __launch_bounds__(256) void s3_filter(
    float* __restrict__ buf, const RowP2* __restrict__ params) {
  const int b = blockIdx.x >> 3, sl = blockIdx.x & 7, t = threadIdx.x;
  const RowP2 p = params[b];
  const unsigned ustar = p.ustar;
  const float invZ = p.invZ;
  const bool need = (p.m < p.cEq);
  float* row = buf + (size_t)b * NV;
  const int base = sl * 4096;
#pragma unroll
  for (int it = 0; it < 4; it++) {
    const int idx = base + (it * 256 + t) * 4;
    if (idx < NV) {
      float4 e4 = *(const float4*)(row + idx);
      float4 o4;
      unsigned k;
      k = __float_as_uint(e4.x);
      o4.x = (k > ustar) ? e4.x * invZ : ((k == ustar) ? (need ? -e4.x : e4.x * invZ) : 0.f);
      k = __float_as_uint(e4.y);
      o4.y = (k > ustar) ? e4.y * invZ : ((k == ustar) ? (need ? -e4.y : e4.y * invZ) : 0.f);
      k = __float_as_uint(e4.z);
      o4.z = (k > ustar) ? e4.z * invZ : ((k == ustar) ? (need ? -e4.z : e4.z * invZ) : 0.f);
      k = __float_as_uint(e4.w);
      o4.w = (k > ustar) ? e4.w * invZ : ((k == ustar) ? (need ? -e4.w : e4.w * invZ) : 0.f);
      *(float4*)(row + idx) = o4;
    }
  }
}

// ---------------- s5_tie: rare tie-rank fixup (no-op unless m < cEq) ----------------
__global__ __launch_bounds__(256) void s5_tie(
    float* __restrict__ buf, const RowP2* __restrict__ params) {
  const int b = blockIdx.x, t = threadIdx.x;
  const RowP2 p = params[b];
  if (p.m >= p.cEq) return;
  const int m = p.m;
  const float invZ = p.invZ;
  float* row = buf + (size_t)b * NV;
  __shared__ int s_rank[256];
  const int CH = NV / 256;  // 125
  const int base = t * CH, end = base + CH;
  int myc = 0;
  for (int v = base; v < end; v++) myc += (row[v] < 0.f);
  s_rank[t] = myc;
  __syncthreads();
  for (int off = 1; off < 256; off <<= 1) {
    const int v0 = s_rank[t];
    const int vn = (t >= off) ? s_rank[t - off] : 0;
    __syncthreads();
    s_rank[t] = v0 + vn;
    __syncthreads();
  }
  int r = (t > 0) ? s_rank[t - 1] : 0;
  for (int v = base; v < end; v++) {
    const float f = row[v];
    if (f < 0.f) {
      row[v] = (r < m) ? (-f) * invZ : 0.f;
      r++;
    }
  }
}

extern "C" void kernel_launch(void* const* d_in, const int* in_sizes, int n_in,
                              void* d_out, int out_size, void* d_ws, size_t ws_size,
                              hipStream_t stream) {
  (void)in_sizes; (void)n_in; (void)out_size; (void)ws_size;
  const float* hidden = (const float*)d_in[0];
  const float* emb    = (const float*)d_in[1];
  const int*   toks   = (const int*)d_in[2];
  const float* pres   = (const float*)d_in[3];
  const float* freq   = (const float*)d_in[4];
  const float* temp   = (const float*)d_in[5];
  const float* topp   = (const float*)d_in[6];
  const int*   topk   = (const int*)d_in[7];
  float* out = (float*)d_out;

  // ws layout: A3 (1,048,576) + rowmax (1,024, zeroed by convert_A) + params (10,240)
  const size_t offA3  = 0;
  const size_t offRM  = 1048576;
  const size_t offPar = offRM + 1024;

  _Float16* A3 = (_Float16*)((char*)d_ws + offA3);
  unsigned* rowmax = (unsigned*)((char*)d_ws + offRM);
  RowP2* params = (RowP2*)((char*)d_ws + offPar);

  convert_A<<<256, 256, 0, stream>>>(hidden, A3, rowmax);
  gemm_f16s<<<NGBLK, 256, 0, stream>>>(emb, A3, temp, rowmax, out);
  sample_select<<<NB, 1024, 0, stream>>>(out, rowmax, toks, pres, freq,
                                         temp, topp, topk, params);
  s3_filter<<<NB * 8, 256, 0, stream>>>(out, params);
  s5_tie<<<NB, 256, 0, stream>>>(out, params);
}